// Round 1
// baseline (62.816 us; speedup 1.0000x reference)
//
#include <hip/hip_runtime.h>

// WeightedCCEDiceLossWithSoftmax — fully fused single-pass reduction.
// Inputs: d_in[0] predictions [B,8] f32, d_in[1] ground_truth one-hot [B,8] f32,
//         d_in[2] class_weights [8] f32. Output: d_out[0] scalar f32.

#define NBLOCKS 2048
#define NTHREADS 256

__device__ __forceinline__ float fast_exp(float x) { return __expf(x); }

// ws layout (floats/uints, 4B each):
//   [0..23]  uint counts: [0..7]=gt histogram (row sums), [8..15]=pred histogram
//            (col sums), [16..23]=tp (diag)
//   [32..32+NBLOCKS) float per-block CE partial sums
__global__ void wcd_init(unsigned int* __restrict__ cnt) {
    int i = threadIdx.x;
    if (i < 24) cnt[i] = 0u;
}

__global__ __launch_bounds__(NTHREADS) void wcd_main(
    const float* __restrict__ pred, const float* __restrict__ gt,
    const float* __restrict__ cw, unsigned int* __restrict__ cnt,
    float* __restrict__ ce_partial, int B)
{
    __shared__ float sw[8];
    __shared__ unsigned int scnt[24];
    __shared__ float sred[NTHREADS];

    const int tid = threadIdx.x;
    if (tid < 8)  sw[tid]   = cw[tid];
    if (tid < 24) scnt[tid] = 0u;
    __syncthreads();

    float ce = 0.0f;
    const int stride = gridDim.x * blockDim.x;
    for (int i = blockIdx.x * blockDim.x + tid; i < B; i += stride) {
        const float4* p4 = reinterpret_cast<const float4*>(pred) + 2 * (size_t)i;
        const float4* g4 = reinterpret_cast<const float4*>(gt)   + 2 * (size_t)i;
        float4 a0 = p4[0], a1 = p4[1];
        float4 b0 = g4[0], b1 = g4[1];
        float x[8] = {a0.x, a0.y, a0.z, a0.w, a1.x, a1.y, a1.z, a1.w};
        float g[8] = {b0.x, b0.y, b0.z, b0.w, b1.x, b1.y, b1.z, b1.w};

        // argmax of predictions (first-occurrence, == argmax of softmax)
        float m = x[0]; int am = 0;
        #pragma unroll
        for (int j = 1; j < 8; ++j) { if (x[j] > m) { m = x[j]; am = j; } }

        // ground-truth class (one-hot: exactly one 1.0)
        int gi = 0;
        #pragma unroll
        for (int j = 1; j < 8; ++j) { if (g[j] > 0.5f) gi = j; }

        // p = softmax(x)  (max-subtracted, matches jax.nn.softmax)
        float e[8], se = 0.0f;
        #pragma unroll
        for (int j = 0; j < 8; ++j) { e[j] = fast_exp(x[j] - m); se += e[j]; }
        float inv = 1.0f / se;

        // log_softmax(p)[gi] = p[gi] - log(sum_k exp(p[k]));  p in [0,1] -> no
        // max subtraction needed for stability.
        float s2 = 0.0f, pg = 0.0f;
        #pragma unroll
        for (int j = 0; j < 8; ++j) {
            float pj = e[j] * inv;
            s2 += fast_exp(pj);
            if (j == gi) pg = pj;
        }
        ce += sw[gi] * (__logf(s2) - pg);

        // confusion-matrix marginals
        atomicAdd(&scnt[gi], 1u);          // row sum (gt class)
        atomicAdd(&scnt[8 + am], 1u);      // col sum (pred class)
        if (gi == am) atomicAdd(&scnt[16 + gi], 1u);  // diagonal (tp)
    }

    // deterministic block reduction of CE -> one partial per block
    sred[tid] = ce;
    __syncthreads();
    #pragma unroll
    for (int s = NTHREADS / 2; s > 0; s >>= 1) {
        if (tid < s) sred[tid] += sred[tid + s];
        __syncthreads();
    }
    if (tid == 0) ce_partial[blockIdx.x] = sred[0];

    // counts: exact integers, atomic order irrelevant -> deterministic
    if (tid < 24 && scnt[tid] != 0u) atomicAdd(&cnt[tid], scnt[tid]);
}

__global__ __launch_bounds__(NTHREADS) void wcd_finalize(
    const unsigned int* __restrict__ cnt, const float* __restrict__ ce_partial,
    const float* __restrict__ cw, float* __restrict__ out, int B)
{
    __shared__ float sred[NTHREADS];
    const int tid = threadIdx.x;
    float s = 0.0f;
    for (int i = tid; i < NBLOCKS; i += NTHREADS) s += ce_partial[i];
    sred[tid] = s;
    __syncthreads();
    #pragma unroll
    for (int k = NTHREADS / 2; k > 0; k >>= 1) {
        if (tid < k) sred[tid] += sred[tid + k];
        __syncthreads();
    }
    if (tid == 0) {
        const float EPS = 1e-8f;
        float dice_loss = 0.0f;
        #pragma unroll
        for (int c = 0; c < 8; ++c) {
            float tp    = (float)cnt[16 + c];
            float rowc  = (float)cnt[c];       // tp + fn
            float colc  = (float)cnt[8 + c];   // tp + fp
            float dice  = (tp + EPS) / (rowc + colc - tp + EPS);
            dice_loss  += (1.0f - dice) * cw[c];
        }
        dice_loss *= (1.0f / 8.0f);
        float cce = sred[0] / (float)B;
        out[0] = cce * 1.0f + dice_loss * 0.5f;
    }
}

extern "C" void kernel_launch(void* const* d_in, const int* in_sizes, int n_in,
                              void* d_out, int out_size, void* d_ws, size_t ws_size,
                              hipStream_t stream) {
    const float* pred = (const float*)d_in[0];
    const float* gt   = (const float*)d_in[1];
    const float* cw   = (const float*)d_in[2];
    float* out        = (float*)d_out;

    const int C = in_sizes[2];          // 8
    const int B = in_sizes[0] / C;      // 4194304

    unsigned int* cnt  = (unsigned int*)d_ws;
    float* ce_partial  = (float*)d_ws + 32;

    wcd_init<<<1, 64, 0, stream>>>(cnt);
    wcd_main<<<NBLOCKS, NTHREADS, 0, stream>>>(pred, gt, cw, cnt, ce_partial, B);
    wcd_finalize<<<1, NTHREADS, 0, stream>>>(cnt, ce_partial, cw, out, B);
}